// Round 2
// baseline (1512.100 us; speedup 1.0000x reference)
//
#include <hip/hip_runtime.h>

// Problem constants
#define BATCH 4096
#define FEATS 26
#define BAG   8
#define EDIM  64
#define INDIM 1664   // 26*64

typedef short bf16x8 __attribute__((ext_vector_type(8)));
typedef float f32x4  __attribute__((ext_vector_type(4)));
typedef unsigned short u16x8 __attribute__((ext_vector_type(8)));

__device__ __forceinline__ unsigned short f2bf(float f) {
    unsigned u = __float_as_uint(f);
    unsigned r = (u + 0x7FFFu + ((u >> 16) & 1u)) >> 16;
    return (unsigned short)r;
}
__device__ __forceinline__ float bf2f(unsigned short h) {
    return __uint_as_float((unsigned)h << 16);
}
// async global->LDS, 16B per lane. HW dst = wave-uniform base + lane*16.
__device__ __forceinline__ void async_cp16(const void* g, void* lds_base_uniform) {
    __builtin_amdgcn_global_load_lds(
        (const __attribute__((address_space(1))) unsigned int*)g,
        (__attribute__((address_space(3))) unsigned int*)lds_base_uniform,
        16, 0, 0);
}
// s_waitcnt with only vmcnt constrained (lgkm=15, exp=7 i.e. no wait)
#define WAITCNT_VM(n) __builtin_amdgcn_s_waitcnt(0x0F70 | (n))

// ---------------- batched weight transpose + fp32->bf16 (1 launch, 6 weights) ----
// in: [R,C] fp32  ->  out: [C,R] bf16.  blockIdx.z selects the weight.
__global__ __launch_bounds__(256) void transpose_all(
    const float* __restrict__ w10, unsigned short* __restrict__ o10,
    const float* __restrict__ w20, unsigned short* __restrict__ o20,
    const float* __restrict__ w11, unsigned short* __restrict__ o11,
    const float* __restrict__ w21, unsigned short* __restrict__ o21,
    const float* __restrict__ w12, unsigned short* __restrict__ o12,
    const float* __restrict__ w22, unsigned short* __restrict__ o22)
{
    const float* in; unsigned short* out; int R, C;
    switch (blockIdx.z) {
        case 0:  in = w10; out = o10; R = INDIM; C = 1024;  break;
        case 1:  in = w20; out = o20; R = 1024;  C = INDIM; break;
        case 2:  in = w11; out = o11; R = INDIM; C = 1024;  break;
        case 3:  in = w21; out = o21; R = 1024;  C = INDIM; break;
        case 4:  in = w12; out = o12; R = INDIM; C = 512;   break;
        default: in = w22; out = o22; R = 512;   C = INDIM; break;
    }
    const int c0 = blockIdx.x * 64, r0 = blockIdx.y * 64;
    if (c0 >= C || r0 >= R) return;

    __shared__ unsigned short tile[64][65];
    const int t = threadIdx.x;
    const int tc = t & 63, tr = t >> 6;
#pragma unroll
    for (int i = 0; i < 16; ++i) {
        int r = tr + i * 4;
        tile[r][tc] = f2bf(in[(long long)(r0 + r) * C + c0 + tc]);
    }
    __syncthreads();
    const int wr = t >> 3, wc = t & 7;
#pragma unroll
    for (int half = 0; half < 2; ++half) {
        int row = wr + half * 32;
        u16x8 v;
#pragma unroll
        for (int j = 0; j < 8; ++j) v[j] = tile[wc * 8 + j][row];
        *(u16x8*)(out + (long long)(c0 + row) * R + r0 + wc * 8) = v;
    }
}

// ---------------- embedding bag: gather + sum-pool -> bf16 ----------------
// Also zeroes the grid-barrier counters for mlp_chain (ws is re-poisoned
// each iteration, so the counters must be re-zeroed each iteration).
__global__ __launch_bounds__(256) void embed_pool(
    const int* __restrict__ x, const float* __restrict__ emb,
    unsigned short* __restrict__ feat, unsigned* __restrict__ bar)
{
    if (blockIdx.x == 0 && threadIdx.x < 8) bar[threadIdx.x] = 0;
    int bag  = blockIdx.x * 4 + (threadIdx.x >> 6);
    int lane = threadIdx.x & 63;
    int b = bag / FEATS;
    int f = bag - b * FEATS;
    const int* xs = x + (long long)bag * BAG;
    float s = 0.f;
#pragma unroll
    for (int l = 0; l < BAG; ++l) {
        int id = xs[l];
        s += emb[(long long)id * EDIM + lane];
    }
    feat[(long long)b * INDIM + f * EDIM + lane] = f2bf(s);
}

// ------------- persistent fused MLP: 6 GEMM stages + head, grid barriers ----
// GEMM stage: 128x128 tile, BK=32, 4-deep async global_load_lds pipeline,
// 512 threads = 8 waves; wave tile 64x32 (wm=wave&1, wn=wave>>1).
// LDS: 4 buf x (A 8KB + B 8KB) = 64 KB -> 2 blocks/CU; grid 512 co-resident.
// XOR swizzle: LDS slot (row, s) holds global k-chunk s ^ ((row>>1)&3) (16B chunks).
#define NBUF 4

__device__ void run_stage(
    unsigned short* As, unsigned short* Bs,
    const unsigned short* __restrict__ A, const unsigned short* __restrict__ Bt,
    const float* __restrict__ bias, const unsigned short* __restrict__ res,
    unsigned short* __restrict__ O, int N, int K)
{
    const int t    = threadIdx.x;
    const int wave = t >> 6, lane = t & 63;
    const int wm = wave & 1, wn = wave >> 1;       // wn in 0..3
    const int lm = lane & 15, quad = lane >> 4;
    const int srow = lane >> 2;
    const int sq   = (lane & 3) ^ ((lane >> 3) & 3);
    const int slot = (quad ^ ((lm >> 1) & 3)) * 8;

    const int nx = N >> 7;                // col tiles
    const int nTiles = (BATCH >> 7) * nx; // 32 * nx
    const int T = K >> 5;

    for (int tile = blockIdx.x; tile < nTiles; tile += (int)gridDim.x) {
        const int trow = tile / nx;
        const int bRow = trow << 7;
        const int bCol = (tile - trow * nx) << 7;

        const unsigned short* Ag = A  + (long long)(bRow + wave * 16 + srow) * K + sq * 8;
        const unsigned short* Bg = Bt + (long long)(bCol + wave * 16 + srow) * K + sq * 8;
        unsigned short* AsW = As + wave * 512;   // + buf*4096
        unsigned short* BsW = Bs + wave * 512;

        f32x4 acc[4][2] = {};

#define ISSUE(tile_)  do { int _b = (tile_) & (NBUF - 1);                         \
        async_cp16(Ag + (long long)(tile_) * 32, AsW + _b * 4096);                \
        async_cp16(Bg + (long long)(tile_) * 32, BsW + _b * 4096); } while (0)

#define COMPUTE(tile_) do { int _b = (tile_) & (NBUF - 1);                        \
        const unsigned short* _a = As + _b * 4096;                                \
        const unsigned short* _bp = Bs + _b * 4096;                               \
        bf16x8 af[4], bf[2];                                                      \
        _Pragma("unroll")                                                         \
        for (int i = 0; i < 4; ++i)                                               \
            af[i] = *(const bf16x8*)&_a[(wm * 64 + i * 16 + lm) * 32 + slot];     \
        _Pragma("unroll")                                                         \
        for (int j = 0; j < 2; ++j)                                               \
            bf[j] = *(const bf16x8*)&_bp[(wn * 32 + j * 16 + lm) * 32 + slot];    \
        _Pragma("unroll")                                                         \
        for (int i = 0; i < 4; ++i)                                               \
            _Pragma("unroll")                                                     \
            for (int j = 0; j < 2; ++j)                                           \
                acc[i][j] = __builtin_amdgcn_mfma_f32_16x16x32_bf16(              \
                    af[i], bf[j], acc[i][j], 0, 0, 0); } while (0)

        ISSUE(0);
        ISSUE(1);
        for (int tt = 0; tt < T - 2; ++tt) {
            ISSUE(tt + 2);             // lands in buf[(tt+2)&3]: reads done 2 iters ago
            WAITCNT_VM(4);             // tile tt's 2 loads complete
            asm volatile("" ::: "memory");
            __builtin_amdgcn_s_barrier();
            asm volatile("" ::: "memory");
            COMPUTE(tt);
        }
        WAITCNT_VM(2);
        asm volatile("" ::: "memory");
        __builtin_amdgcn_s_barrier();
        asm volatile("" ::: "memory");
        COMPUTE(T - 2);
        WAITCNT_VM(0);
        asm volatile("" ::: "memory");
        __builtin_amdgcn_s_barrier();
        asm volatile("" ::: "memory");
        COMPUTE(T - 1);

        // ---- epilogue: bias (+res) (+relu), bf16 out ----
#pragma unroll
        for (int i = 0; i < 4; ++i) {
#pragma unroll
            for (int j = 0; j < 2; ++j) {
                int col = bCol + wn * 32 + j * 16 + lm;
                float bv = bias[col];
#pragma unroll
                for (int rr = 0; rr < 4; ++rr) {
                    int row = bRow + wm * 64 + i * 16 + quad * 4 + rr;
                    float v = acc[i][j][rr] + bv;
                    if (res) v += bf2f(res[(long long)row * N + col]);
                    v = fmaxf(v, 0.f);
                    O[(long long)row * N + col] = f2bf(v);
                }
            }
        }
#undef ISSUE
#undef COMPUTE
    }
}

__device__ __forceinline__ void grid_barrier(unsigned* bar, int slotIdx) {
    __syncthreads();
    if (threadIdx.x == 0) {
        __hip_atomic_fetch_add(&bar[slotIdx], 1u, __ATOMIC_ACQ_REL,
                               __HIP_MEMORY_SCOPE_AGENT);
        while (__hip_atomic_load(&bar[slotIdx], __ATOMIC_ACQUIRE,
                                 __HIP_MEMORY_SCOPE_AGENT) < gridDim.x)
            __builtin_amdgcn_s_sleep(8);
    }
    __syncthreads();
}

__global__ __launch_bounds__(512, 4) void mlp_chain(
    unsigned short* __restrict__ feat, unsigned short* __restrict__ h,
    const unsigned short* __restrict__ w10t, const float* __restrict__ b10,
    const unsigned short* __restrict__ w20t, const float* __restrict__ b20,
    const unsigned short* __restrict__ w11t, const float* __restrict__ b11,
    const unsigned short* __restrict__ w21t, const float* __restrict__ b21,
    const unsigned short* __restrict__ w12t, const float* __restrict__ b12,
    const unsigned short* __restrict__ w22t, const float* __restrict__ b22,
    const float* __restrict__ linw, const float* __restrict__ linb,
    float* __restrict__ out, unsigned* bar)
{
    __shared__ unsigned short As[NBUF * 128 * 32];
    __shared__ unsigned short Bs[NBUF * 128 * 32];

    run_stage(As, Bs, feat, w10t, b10, nullptr, h,    1024,  INDIM);
    grid_barrier(bar, 0);
    run_stage(As, Bs, h,    w20t, b20, feat,    feat, INDIM, 1024);
    grid_barrier(bar, 1);
    run_stage(As, Bs, feat, w11t, b11, nullptr, h,    1024,  INDIM);
    grid_barrier(bar, 2);
    run_stage(As, Bs, h,    w21t, b21, feat,    feat, INDIM, 1024);
    grid_barrier(bar, 3);
    run_stage(As, Bs, feat, w12t, b12, nullptr, h,    512,   INDIM);
    grid_barrier(bar, 4);
    run_stage(As, Bs, h,    w22t, b22, feat,    feat, INDIM, 512);
    grid_barrier(bar, 5);

    // ---- head: 512 blocks x 8 waves = 4096 rows, one row per wave ----
    const int wave = threadIdx.x >> 6, lane = threadIdx.x & 63;
    int row = blockIdx.x * 8 + wave;
    if (row < BATCH) {
        const unsigned short* fr = feat + (long long)row * INDIM;
        float s = 0.f;
#pragma unroll
        for (int it = 0; it < INDIM / 64; ++it)
            s += bf2f(fr[it * 64 + lane]) * linw[it * 64 + lane];
#pragma unroll
        for (int off = 32; off; off >>= 1)
            s += __shfl_down(s, off, 64);
        if (lane == 0)
            out[row] = 1.f / (1.f + __expf(-(s + linb[0])));
    }
}

extern "C" void kernel_launch(void* const* d_in, const int* in_sizes, int n_in,
                              void* d_out, int out_size, void* d_ws, size_t ws_size,
                              hipStream_t stream) {
    const int*   x    = (const int*)  d_in[0];
    const float* emb  = (const float*)d_in[1];
    const float* w1_0 = (const float*)d_in[2];
    const float* b1_0 = (const float*)d_in[3];
    const float* w2_0 = (const float*)d_in[4];
    const float* b2_0 = (const float*)d_in[5];
    const float* w1_1 = (const float*)d_in[6];
    const float* b1_1 = (const float*)d_in[7];
    const float* w2_1 = (const float*)d_in[8];
    const float* b2_1 = (const float*)d_in[9];
    const float* w1_2 = (const float*)d_in[10];
    const float* b1_2 = (const float*)d_in[11];
    const float* w2_2 = (const float*)d_in[12];
    const float* b2_2 = (const float*)d_in[13];
    const float* linw = (const float*)d_in[14];
    const float* linb = (const float*)d_in[15];
    float* out = (float*)d_out;

    // ws layout (bf16 elements)
    unsigned short* feat = (unsigned short*)d_ws;            // [4096,1664]
    unsigned short* h    = feat + (long long)BATCH * INDIM;  // [4096,1024]
    unsigned short* p    = h + (long long)BATCH * 1024;
    unsigned short* w1_0t = p; p += 1024 * INDIM;
    unsigned short* w2_0t = p; p += INDIM * 1024;
    unsigned short* w1_1t = p; p += 1024 * INDIM;
    unsigned short* w2_1t = p; p += INDIM * 1024;
    unsigned short* w1_2t = p; p += 512 * INDIM;
    unsigned short* w2_2t = p; p += INDIM * 512;
    unsigned*       bar   = (unsigned*)p;                    // 8 counters

    // 0) all weight transposes in ONE launch (z = weight index)
    transpose_all<<<dim3(26, 26, 6), 256, 0, stream>>>(
        w1_0, w1_0t, w2_0, w2_0t, w1_1, w1_1t, w2_1, w2_1t, w1_2, w1_2t, w2_2, w2_2t);

    // 1) embedding bag -> bf16 feat (also zeroes barrier counters)
    embed_pool<<<BATCH * FEATS / 4, 256, 0, stream>>>(x, emb, feat, bar);

    // 2+3) persistent fused MLP chain (6 GEMMs + head), 512 blocks = 2/CU
    mlp_chain<<<512, 512, 0, stream>>>(
        feat, h, w1_0t, b1_0, w2_0t, b2_0, w1_1t, b1_1, w2_1t, b2_1,
        w1_2t, b1_2, w2_2t, b2_2, linw, linb, out, bar);
}

// Round 3
// 878.542 us; speedup vs baseline: 1.7211x; 1.7211x over previous
//
#include <hip/hip_runtime.h>

// Problem constants
#define BATCH 4096
#define FEATS 26
#define BAG   8
#define EDIM  64
#define INDIM 1664   // 26*64
#define NENT  (BATCH * FEATS * BAG)   // 851968 (id, bag) entries
#define NBUCK 1024                    // id >> 10 -> bucket (256KB table window)

typedef short bf16x8 __attribute__((ext_vector_type(8)));
typedef float f32x4  __attribute__((ext_vector_type(4)));
typedef unsigned short u16x8 __attribute__((ext_vector_type(8)));

__device__ __forceinline__ unsigned short f2bf(float f) {
    unsigned u = __float_as_uint(f);
    unsigned r = (u + 0x7FFFu + ((u >> 16) & 1u)) >> 16;
    return (unsigned short)r;
}
__device__ __forceinline__ float bf2f(unsigned short h) {
    return __uint_as_float((unsigned)h << 16);
}
// async global->LDS, 16B per lane. HW dst = wave-uniform base + lane*16.
__device__ __forceinline__ void async_cp16(const void* g, void* lds_base_uniform) {
    __builtin_amdgcn_global_load_lds(
        (const __attribute__((address_space(1))) unsigned int*)g,
        (__attribute__((address_space(3))) unsigned int*)lds_base_uniform,
        16, 0, 0);
}
// s_waitcnt with only vmcnt constrained (lgkm=15, exp=7 i.e. no wait)
#define WAITCNT_VM(n) __builtin_amdgcn_s_waitcnt(0x0F70 | (n))

// ---------------- batched weight transpose + fp32->bf16 (1 launch, 6 weights) ----
__global__ __launch_bounds__(256) void transpose_all(
    const float* __restrict__ w10, unsigned short* __restrict__ o10,
    const float* __restrict__ w20, unsigned short* __restrict__ o20,
    const float* __restrict__ w11, unsigned short* __restrict__ o11,
    const float* __restrict__ w21, unsigned short* __restrict__ o21,
    const float* __restrict__ w12, unsigned short* __restrict__ o12,
    const float* __restrict__ w22, unsigned short* __restrict__ o22)
{
    const float* in; unsigned short* out; int R, C;
    switch (blockIdx.z) {
        case 0:  in = w10; out = o10; R = INDIM; C = 1024;  break;
        case 1:  in = w20; out = o20; R = 1024;  C = INDIM; break;
        case 2:  in = w11; out = o11; R = INDIM; C = 1024;  break;
        case 3:  in = w21; out = o21; R = 1024;  C = INDIM; break;
        case 4:  in = w12; out = o12; R = INDIM; C = 512;   break;
        default: in = w22; out = o22; R = 512;   C = INDIM; break;
    }
    const int c0 = blockIdx.x * 64, r0 = blockIdx.y * 64;
    if (c0 >= C || r0 >= R) return;

    __shared__ unsigned short tile[64][65];
    const int t = threadIdx.x;
    const int tc = t & 63, tr = t >> 6;
#pragma unroll
    for (int i = 0; i < 16; ++i) {
        int r = tr + i * 4;
        tile[r][tc] = f2bf(in[(long long)(r0 + r) * C + c0 + tc]);
    }
    __syncthreads();
    const int wr = t >> 3, wc = t & 7;
#pragma unroll
    for (int half = 0; half < 2; ++half) {
        int row = wr + half * 32;
        u16x8 v;
#pragma unroll
        for (int j = 0; j < 8; ++j) v[j] = tile[wc * 8 + j][row];
        *(u16x8*)(out + (long long)(c0 + row) * R + r0 + wc * 8) = v;
    }
}

// ============ embedding path: bucket-sorted gather (DRAM locality) ============
// 1) zero pooled accumulator + bucket counters
__global__ __launch_bounds__(256) void zero_pooled(
    float* __restrict__ pooled, unsigned* __restrict__ cnts /* cnt[1024]+cur[1024] */)
{
    int i = blockIdx.x * 256 + threadIdx.x;        // 6656 blocks: i < 1703936
    *(f32x4*)(pooled + (long long)i * 4) = (f32x4){0.f, 0.f, 0.f, 0.f};
    if (i < 2 * NBUCK) cnts[i] = 0;
}

// 2) histogram of id>>10 (LDS-aggregated)
__global__ __launch_bounds__(256) void hist_ids(
    const int* __restrict__ x, unsigned* __restrict__ cnt)
{
    __shared__ unsigned lc[NBUCK];
    for (int i = threadIdx.x; i < NBUCK; i += 256) lc[i] = 0;
    __syncthreads();
    for (int i = blockIdx.x * 256 + threadIdx.x; i < NENT; i += gridDim.x * 256)
        atomicAdd(&lc[((unsigned)x[i]) >> 10], 1u);
    __syncthreads();
    for (int i = threadIdx.x; i < NBUCK; i += 256)
        if (lc[i]) atomicAdd(&cnt[i], lc[i]);
}

// 3) exclusive scan of 1024 bucket counts -> cursor array (single wave)
__global__ __launch_bounds__(64) void scan_buckets(
    const unsigned* __restrict__ cnt, unsigned* __restrict__ cur)
{
    const int lane = threadIdx.x;
    unsigned v[16], s = 0;
#pragma unroll
    for (int j = 0; j < 16; ++j) { v[j] = cnt[lane * 16 + j]; s += v[j]; }
    unsigned incl = s;
#pragma unroll
    for (int off = 1; off < 64; off <<= 1) {
        unsigned t = __shfl_up(incl, off, 64);
        if (lane >= off) incl += t;
    }
    unsigned run = incl - s;                       // exclusive prefix
#pragma unroll
    for (int j = 0; j < 16; ++j) { cur[lane * 16 + j] = run; run += v[j]; }
}

// 4) scatter (id, bag) pairs into bucket-ordered array
__global__ __launch_bounds__(256) void scatter_ids(
    const int* __restrict__ x, unsigned* __restrict__ cur, uint2* __restrict__ srt)
{
    for (int i = blockIdx.x * 256 + threadIdx.x; i < NENT; i += gridDim.x * 256) {
        unsigned id = (unsigned)x[i];
        unsigned slot = atomicAdd(&cur[id >> 10], 1u);
        srt[slot] = make_uint2(id, (unsigned)(i >> 3));   // bag index = i/8
    }
}

// 5) gather in bucket order, accumulate into fp32 pooled via HW f32 atomics.
//    Concurrent waves walk a contiguous window of the sorted stream ->
//    active table window ~5MB -> L2/L3 resident, DRAM near-sequential.
__global__ __launch_bounds__(256) void gather_accum(
    const uint2* __restrict__ srt, const float* __restrict__ emb,
    float* __restrict__ pooled)
{
    const int nw   = (gridDim.x * 256) >> 6;
    const int w    = (blockIdx.x * 256 + threadIdx.x) >> 6;
    const int lane = threadIdx.x & 63;
    for (int e = w; e < NENT; e += nw) {
        uint2 s = srt[e];
        float v = emb[(long long)s.x * EDIM + lane];
        unsafeAtomicAdd(&pooled[(long long)s.y * EDIM + lane], v);
    }
}

// 6) pooled fp32 -> feat bf16
__global__ __launch_bounds__(256) void convert_feat(
    const float* __restrict__ pooled, unsigned short* __restrict__ feat)
{
    int i = blockIdx.x * 256 + threadIdx.x;        // 3328 blocks: i < 851968
    f32x4 a = *(const f32x4*)(pooled + (long long)i * 8);
    f32x4 b = *(const f32x4*)(pooled + (long long)i * 8 + 4);
    u16x8 o;
#pragma unroll
    for (int j = 0; j < 4; ++j) { o[j] = f2bf(a[j]); o[j + 4] = f2bf(b[j]); }
    *(u16x8*)(feat + (long long)i * 8) = o;
}

// ------------- bf16 MFMA GEMM, 128x128 tile, BK=32, 4-deep async pipeline ----
// (round-0 proven config) 512 threads = 8 waves; wave tile 64x32.
// LDS: 4 buffers x (A 8KB + B 8KB) = 64 KB. One s_barrier per K-iter, fine vmcnt.
// XOR swizzle: LDS slot (row, s) holds global k-chunk s ^ ((row>>1)&3)  (16B chunks).
#define NBUF 4
__global__ __launch_bounds__(512) void gemm_bf16(
    const unsigned short* __restrict__ A, const unsigned short* __restrict__ Wt,
    const float* __restrict__ bias, const unsigned short* __restrict__ res,
    unsigned short* __restrict__ out, int M, int N, int K, int do_relu)
{
    __shared__ unsigned short As[NBUF * 128 * 32];
    __shared__ unsigned short Bs[NBUF * 128 * 32];

    const int t    = threadIdx.x;
    const int bCol = blockIdx.x * 128;
    const int bRow = blockIdx.y * 128;
    const int wave = t >> 6, lane = t & 63;
    const int wm = wave & 1, wn = wave >> 1;       // wn in 0..3
    const int lm = lane & 15, quad = lane >> 4;

    const int srow = lane >> 2;
    const int sq   = (lane & 3) ^ ((lane >> 3) & 3);
    const unsigned short* Ag = A  + (long long)(bRow + wave * 16 + srow) * K + sq * 8;
    const unsigned short* Bg = Wt + (long long)(bCol + wave * 16 + srow) * K + sq * 8;
    unsigned short* AsW = As + wave * 512;   // + buf*4096
    unsigned short* BsW = Bs + wave * 512;

    const int T = K / 32;
    f32x4 acc[4][2] = {};
    const int slot = (quad ^ ((lm >> 1) & 3)) * 8;

#define ISSUE(tile_)  do { int _b = (tile_) & (NBUF - 1);                         \
        async_cp16(Ag + (long long)(tile_) * 32, AsW + _b * 4096);                \
        async_cp16(Bg + (long long)(tile_) * 32, BsW + _b * 4096); } while (0)

#define COMPUTE(tile_) do { int _b = (tile_) & (NBUF - 1);                        \
        const unsigned short* _a = As + _b * 4096;                                \
        const unsigned short* _bp = Bs + _b * 4096;                               \
        bf16x8 af[4], bf[2];                                                      \
        _Pragma("unroll")                                                         \
        for (int i = 0; i < 4; ++i)                                               \
            af[i] = *(const bf16x8*)&_a[(wm * 64 + i * 16 + lm) * 32 + slot];     \
        _Pragma("unroll")                                                         \
        for (int j = 0; j < 2; ++j)                                               \
            bf[j] = *(const bf16x8*)&_bp[(wn * 32 + j * 16 + lm) * 32 + slot];    \
        _Pragma("unroll")                                                         \
        for (int i = 0; i < 4; ++i)                                               \
            _Pragma("unroll")                                                     \
            for (int j = 0; j < 2; ++j)                                           \
                acc[i][j] = __builtin_amdgcn_mfma_f32_16x16x32_bf16(              \
                    af[i], bf[j], acc[i][j], 0, 0, 0); } while (0)

    ISSUE(0);
    ISSUE(1);
    for (int tt = 0; tt < T - 2; ++tt) {
        ISSUE(tt + 2);                 // lands in buf[(tt+2)&3] = buf[(tt-2)&3]: reads done
        WAITCNT_VM(4);                 // tile tt's 2 loads complete (t+1,t+2 still in flight)
        asm volatile("" ::: "memory");
        __builtin_amdgcn_s_barrier();
        asm volatile("" ::: "memory");
        COMPUTE(tt);
    }
    WAITCNT_VM(2);
    asm volatile("" ::: "memory");
    __builtin_amdgcn_s_barrier();
    asm volatile("" ::: "memory");
    COMPUTE(T - 2);
    WAITCNT_VM(0);
    asm volatile("" ::: "memory");
    __builtin_amdgcn_s_barrier();
    asm volatile("" ::: "memory");
    COMPUTE(T - 1);

    // ---- epilogue: bias (+res) (+relu), bf16 out ----
#pragma unroll
    for (int i = 0; i < 4; ++i) {
#pragma unroll
        for (int j = 0; j < 2; ++j) {
            int col = bCol + wn * 32 + j * 16 + lm;
            float bv = bias[col];
#pragma unroll
            for (int r = 0; r < 4; ++r) {
                int row = bRow + wm * 64 + i * 16 + quad * 4 + r;
                float v = acc[i][j][r] + bv;
                if (res) v += bf2f(res[(long long)row * N + col]);
                if (do_relu) v = fmaxf(v, 0.f);
                out[(long long)row * N + col] = f2bf(v);
            }
        }
    }
#undef ISSUE
#undef COMPUTE
}

// ---------------- final linear + sigmoid ----------------
__global__ __launch_bounds__(256) void final_head(
    const unsigned short* __restrict__ feat, const float* __restrict__ lin_w,
    const float* __restrict__ lin_b, float* __restrict__ out)
{
    int row  = blockIdx.x * 4 + (threadIdx.x >> 6);
    int lane = threadIdx.x & 63;
    const unsigned short* fr = feat + (long long)row * INDIM;
    float s = 0.f;
#pragma unroll
    for (int it = 0; it < INDIM / 64; ++it)
        s += bf2f(fr[it * 64 + lane]) * lin_w[it * 64 + lane];
#pragma unroll
    for (int off = 32; off; off >>= 1)
        s += __shfl_down(s, off, 64);
    if (lane == 0)
        out[row] = 1.f / (1.f + __expf(-(s + lin_b[0])));
}

extern "C" void kernel_launch(void* const* d_in, const int* in_sizes, int n_in,
                              void* d_out, int out_size, void* d_ws, size_t ws_size,
                              hipStream_t stream) {
    const int*   x    = (const int*)  d_in[0];
    const float* emb  = (const float*)d_in[1];
    const float* w1_0 = (const float*)d_in[2];
    const float* b1_0 = (const float*)d_in[3];
    const float* w2_0 = (const float*)d_in[4];
    const float* b2_0 = (const float*)d_in[5];
    const float* w1_1 = (const float*)d_in[6];
    const float* b1_1 = (const float*)d_in[7];
    const float* w2_1 = (const float*)d_in[8];
    const float* b2_1 = (const float*)d_in[9];
    const float* w1_2 = (const float*)d_in[10];
    const float* b1_2 = (const float*)d_in[11];
    const float* w2_2 = (const float*)d_in[12];
    const float* b2_2 = (const float*)d_in[13];
    const float* linw = (const float*)d_in[14];
    const float* linb = (const float*)d_in[15];
    float* out = (float*)d_out;

    // ws layout
    unsigned short* feat = (unsigned short*)d_ws;            // [4096,1664] bf16
    unsigned short* h    = feat + (long long)BATCH * INDIM;  // [4096,1024] bf16
    unsigned short* p    = h + (long long)BATCH * 1024;
    unsigned short* w1_0t = p; p += 1024 * INDIM;
    unsigned short* w2_0t = p; p += INDIM * 1024;
    unsigned short* w1_1t = p; p += 1024 * INDIM;
    unsigned short* w2_1t = p; p += INDIM * 1024;
    unsigned short* w1_2t = p; p += 512 * INDIM;
    unsigned short* w2_2t = p; p += INDIM * 512;
    float*  pooled = (float*)p;                              // [4096,1664] fp32
    uint2*  srt    = (uint2*)(pooled + (long long)BATCH * INDIM);   // [851968]
    unsigned* cnts = (unsigned*)(srt + NENT);                // cnt[1024] + cur[1024]
    unsigned* cnt  = cnts;
    unsigned* cur  = cnts + NBUCK;

    // 0) all weight transposes in ONE launch (z = weight index)
    transpose_all<<<dim3(26, 26, 6), 256, 0, stream>>>(
        w1_0, w1_0t, w2_0, w2_0t, w1_1, w1_1t, w2_1, w2_1t, w1_2, w1_2t, w2_2, w2_2t);

    // 1) embedding path: bucket-sorted gather
    zero_pooled<<<(BATCH * INDIM / 4) / 256, 256, 0, stream>>>(pooled, cnts);
    hist_ids<<<256, 256, 0, stream>>>(x, cnt);
    scan_buckets<<<1, 64, 0, stream>>>(cnt, cur);
    scatter_ids<<<1024, 256, 0, stream>>>(x, cur, srt);
    gather_accum<<<4096, 256, 0, stream>>>(srt, emb, pooled);
    convert_feat<<<(NENT) / 256, 256, 0, stream>>>(pooled, feat);

    // 2) residual blocks (round-0 proven GEMM config)
    gemm_bf16<<<dim3(1024/128, BATCH/128), 512, 0, stream>>>(
        feat, w1_0t, b1_0, nullptr, h, BATCH, 1024, INDIM, 1);
    gemm_bf16<<<dim3(INDIM/128, BATCH/128), 512, 0, stream>>>(
        h, w2_0t, b2_0, feat, feat, BATCH, INDIM, 1024, 1);
    gemm_bf16<<<dim3(1024/128, BATCH/128), 512, 0, stream>>>(
        feat, w1_1t, b1_1, nullptr, h, BATCH, 1024, INDIM, 1);
    gemm_bf16<<<dim3(INDIM/128, BATCH/128), 512, 0, stream>>>(
        h, w2_1t, b2_1, feat, feat, BATCH, INDIM, 1024, 1);
    gemm_bf16<<<dim3(512/128, BATCH/128), 512, 0, stream>>>(
        feat, w1_2t, b1_2, nullptr, h, BATCH, 512, INDIM, 1);
    gemm_bf16<<<dim3(INDIM/128, BATCH/128), 512, 0, stream>>>(
        h, w2_2t, b2_2, feat, feat, BATCH, INDIM, 512, 1);

    // 3) head
    final_head<<<BATCH / 4, 256, 0, stream>>>(feat, linw, linb, out);
}

// Round 4
// 762.962 us; speedup vs baseline: 1.9819x; 1.1515x over previous
//
#include <hip/hip_runtime.h>

// Problem constants
#define BATCH 4096
#define FEATS 26
#define BAG   8
#define EDIM  64
#define INDIM 1664   // 26*64

typedef short bf16x8 __attribute__((ext_vector_type(8)));
typedef float f32x4  __attribute__((ext_vector_type(4)));
typedef unsigned short u16x8 __attribute__((ext_vector_type(8)));

__device__ __forceinline__ unsigned short f2bf(float f) {
    unsigned u = __float_as_uint(f);
    unsigned r = (u + 0x7FFFu + ((u >> 16) & 1u)) >> 16;
    return (unsigned short)r;
}
__device__ __forceinline__ float bf2f(unsigned short h) {
    return __uint_as_float((unsigned)h << 16);
}
// async global->LDS, 16B per lane. HW dst = wave-uniform base + lane*16.
__device__ __forceinline__ void async_cp16(const void* g, void* lds_base_uniform) {
    __builtin_amdgcn_global_load_lds(
        (const __attribute__((address_space(1))) unsigned int*)g,
        (__attribute__((address_space(3))) unsigned int*)lds_base_uniform,
        16, 0, 0);
}
// s_waitcnt with only vmcnt constrained (lgkm=15, exp=7 i.e. no wait)
#define WAITCNT_VM(n) __builtin_amdgcn_s_waitcnt(0x0F70 | (n))

// ---------------- batched weight transpose + fp32->bf16 (1 launch, 6 weights) ----
__global__ __launch_bounds__(256) void transpose_all(
    const float* __restrict__ w10, unsigned short* __restrict__ o10,
    const float* __restrict__ w20, unsigned short* __restrict__ o20,
    const float* __restrict__ w11, unsigned short* __restrict__ o11,
    const float* __restrict__ w21, unsigned short* __restrict__ o21,
    const float* __restrict__ w12, unsigned short* __restrict__ o12,
    const float* __restrict__ w22, unsigned short* __restrict__ o22)
{
    const float* in; unsigned short* out; int R, C;
    switch (blockIdx.z) {
        case 0:  in = w10; out = o10; R = INDIM; C = 1024;  break;
        case 1:  in = w20; out = o20; R = 1024;  C = INDIM; break;
        case 2:  in = w11; out = o11; R = INDIM; C = 1024;  break;
        case 3:  in = w21; out = o21; R = 1024;  C = INDIM; break;
        case 4:  in = w12; out = o12; R = INDIM; C = 512;   break;
        default: in = w22; out = o22; R = 512;   C = INDIM; break;
    }
    const int c0 = blockIdx.x * 64, r0 = blockIdx.y * 64;
    if (c0 >= C || r0 >= R) return;

    __shared__ unsigned short tile[64][65];
    const int t = threadIdx.x;
    const int tc = t & 63, tr = t >> 6;
#pragma unroll
    for (int i = 0; i < 16; ++i) {
        int r = tr + i * 4;
        tile[r][tc] = f2bf(in[(long long)(r0 + r) * C + c0 + tc]);
    }
    __syncthreads();
    const int wr = t >> 3, wc = t & 7;
#pragma unroll
    for (int half = 0; half < 2; ++half) {
        int row = wr + half * 32;
        u16x8 v;
#pragma unroll
        for (int j = 0; j < 8; ++j) v[j] = tile[wc * 8 + j][row];
        *(u16x8*)(out + (long long)(c0 + row) * R + r0 + wc * 8) = v;
    }
}

// ---------------- embedding bag: windowed gather + register sum-pool -> bf16 ----
// Each wave owns BPW=4 bags (32 ids, register accumulators, NO atomics, writes
// only 4x128B). Gathers are issued window-by-window over the table (31 windows
// of 8MB = id>>15): resident waves sweep windows near-lockstep, so the active
// table footprint stays ~8-32MB -> dup ids hit L2/L3, DRAM sees ~57%-dense
// quasi-sequential sweeps instead of uniform-random 256B. Worst case (drift)
// degenerates to the round-0 access pattern.
#define BPW 4
#define NWIN 31   // (1e6-1)>>15 == 30
__global__ __launch_bounds__(256) void embed_pool(
    const int* __restrict__ x, const float* __restrict__ emb,
    unsigned short* __restrict__ feat)
{
    const int wave = threadIdx.x >> 6, lane = threadIdx.x & 63;
    const int bag0 = (blockIdx.x * 4 + wave) * BPW;
    const float* embl = emb + lane;

    // element offsets id*64 fit u32 (max ~6.4e7); window = off >> 21 (== id>>15)
    unsigned off[BPW][BAG];
#pragma unroll
    for (int g = 0; g < BPW; ++g)
#pragma unroll
        for (int l = 0; l < BAG; ++l)
            off[g][l] = (unsigned)x[(bag0 + g) * BAG + l] * (unsigned)EDIM;

    float s[BPW] = {};
#pragma unroll 1
    for (unsigned w = 0; w < NWIN; ++w) {
#pragma unroll
        for (int g = 0; g < BPW; ++g)
#pragma unroll
            for (int l = 0; l < BAG; ++l)
                if ((off[g][l] >> 21) == w)
                    s[g] += embl[off[g][l]];
    }
#pragma unroll
    for (int g = 0; g < BPW; ++g) {
        int bag = bag0 + g;
        int b = bag / FEATS, f = bag - b * FEATS;
        feat[(long long)b * INDIM + f * EDIM + lane] = f2bf(s[g]);
    }
}

// ------------- bf16 MFMA GEMM, 128x128 tile, BK=32, 4-deep async pipeline ----
// (round-0 proven config) 512 threads = 8 waves; wave tile 64x32.
// LDS: 4 buffers x (A 8KB + B 8KB) = 64 KB. One s_barrier per K-iter, fine vmcnt.
// XOR swizzle: LDS slot (row, s) holds global k-chunk s ^ ((row>>1)&3)  (16B chunks).
#define NBUF 4
__global__ __launch_bounds__(512) void gemm_bf16(
    const unsigned short* __restrict__ A, const unsigned short* __restrict__ Wt,
    const float* __restrict__ bias, const unsigned short* __restrict__ res,
    unsigned short* __restrict__ out, int M, int N, int K, int do_relu)
{
    __shared__ unsigned short As[NBUF * 128 * 32];
    __shared__ unsigned short Bs[NBUF * 128 * 32];

    const int t    = threadIdx.x;
    const int bCol = blockIdx.x * 128;
    const int bRow = blockIdx.y * 128;
    const int wave = t >> 6, lane = t & 63;
    const int wm = wave & 1, wn = wave >> 1;       // wn in 0..3
    const int lm = lane & 15, quad = lane >> 4;

    const int srow = lane >> 2;
    const int sq   = (lane & 3) ^ ((lane >> 3) & 3);
    const unsigned short* Ag = A  + (long long)(bRow + wave * 16 + srow) * K + sq * 8;
    const unsigned short* Bg = Wt + (long long)(bCol + wave * 16 + srow) * K + sq * 8;
    unsigned short* AsW = As + wave * 512;   // + buf*4096
    unsigned short* BsW = Bs + wave * 512;

    const int T = K / 32;
    f32x4 acc[4][2] = {};
    const int slot = (quad ^ ((lm >> 1) & 3)) * 8;

#define ISSUE(tile_)  do { int _b = (tile_) & (NBUF - 1);                         \
        async_cp16(Ag + (long long)(tile_) * 32, AsW + _b * 4096);                \
        async_cp16(Bg + (long long)(tile_) * 32, BsW + _b * 4096); } while (0)

#define COMPUTE(tile_) do { int _b = (tile_) & (NBUF - 1);                        \
        const unsigned short* _a = As + _b * 4096;                                \
        const unsigned short* _bp = Bs + _b * 4096;                               \
        bf16x8 af[4], bf[2];                                                      \
        _Pragma("unroll")                                                         \
        for (int i = 0; i < 4; ++i)                                               \
            af[i] = *(const bf16x8*)&_a[(wm * 64 + i * 16 + lm) * 32 + slot];     \
        _Pragma("unroll")                                                         \
        for (int j = 0; j < 2; ++j)                                               \
            bf[j] = *(const bf16x8*)&_bp[(wn * 32 + j * 16 + lm) * 32 + slot];    \
        _Pragma("unroll")                                                         \
        for (int i = 0; i < 4; ++i)                                               \
            _Pragma("unroll")                                                     \
            for (int j = 0; j < 2; ++j)                                           \
                acc[i][j] = __builtin_amdgcn_mfma_f32_16x16x32_bf16(              \
                    af[i], bf[j], acc[i][j], 0, 0, 0); } while (0)

    ISSUE(0);
    ISSUE(1);
    for (int tt = 0; tt < T - 2; ++tt) {
        ISSUE(tt + 2);                 // lands in buf[(tt+2)&3] = buf[(tt-2)&3]: reads done
        WAITCNT_VM(4);                 // tile tt's 2 loads complete (t+1,t+2 still in flight)
        asm volatile("" ::: "memory");
        __builtin_amdgcn_s_barrier();
        asm volatile("" ::: "memory");
        COMPUTE(tt);
    }
    WAITCNT_VM(2);
    asm volatile("" ::: "memory");
    __builtin_amdgcn_s_barrier();
    asm volatile("" ::: "memory");
    COMPUTE(T - 2);
    WAITCNT_VM(0);
    asm volatile("" ::: "memory");
    __builtin_amdgcn_s_barrier();
    asm volatile("" ::: "memory");
    COMPUTE(T - 1);

    // ---- epilogue: bias (+res) (+relu), bf16 out ----
#pragma unroll
    for (int i = 0; i < 4; ++i) {
#pragma unroll
        for (int j = 0; j < 2; ++j) {
            int col = bCol + wn * 32 + j * 16 + lm;
            float bv = bias[col];
#pragma unroll
            for (int r = 0; r < 4; ++r) {
                int row = bRow + wm * 64 + i * 16 + quad * 4 + r;
                float v = acc[i][j][r] + bv;
                if (res) v += bf2f(res[(long long)row * N + col]);
                if (do_relu) v = fmaxf(v, 0.f);
                out[(long long)row * N + col] = f2bf(v);
            }
        }
    }
#undef ISSUE
#undef COMPUTE
}

// ---------------- final linear + sigmoid ----------------
__global__ __launch_bounds__(256) void final_head(
    const unsigned short* __restrict__ feat, const float* __restrict__ lin_w,
    const float* __restrict__ lin_b, float* __restrict__ out)
{
    int row  = blockIdx.x * 4 + (threadIdx.x >> 6);
    int lane = threadIdx.x & 63;
    const unsigned short* fr = feat + (long long)row * INDIM;
    float s = 0.f;
#pragma unroll
    for (int it = 0; it < INDIM / 64; ++it)
        s += bf2f(fr[it * 64 + lane]) * lin_w[it * 64 + lane];
#pragma unroll
    for (int off = 32; off; off >>= 1)
        s += __shfl_down(s, off, 64);
    if (lane == 0)
        out[row] = 1.f / (1.f + __expf(-(s + lin_b[0])));
}

extern "C" void kernel_launch(void* const* d_in, const int* in_sizes, int n_in,
                              void* d_out, int out_size, void* d_ws, size_t ws_size,
                              hipStream_t stream) {
    const int*   x    = (const int*)  d_in[0];
    const float* emb  = (const float*)d_in[1];
    const float* w1_0 = (const float*)d_in[2];
    const float* b1_0 = (const float*)d_in[3];
    const float* w2_0 = (const float*)d_in[4];
    const float* b2_0 = (const float*)d_in[5];
    const float* w1_1 = (const float*)d_in[6];
    const float* b1_1 = (const float*)d_in[7];
    const float* w2_1 = (const float*)d_in[8];
    const float* b2_1 = (const float*)d_in[9];
    const float* w1_2 = (const float*)d_in[10];
    const float* b1_2 = (const float*)d_in[11];
    const float* w2_2 = (const float*)d_in[12];
    const float* b2_2 = (const float*)d_in[13];
    const float* linw = (const float*)d_in[14];
    const float* linb = (const float*)d_in[15];
    float* out = (float*)d_out;

    // ws layout (bf16 elements)
    unsigned short* feat = (unsigned short*)d_ws;            // [4096,1664]
    unsigned short* h    = feat + (long long)BATCH * INDIM;  // [4096,1024]
    unsigned short* p    = h + (long long)BATCH * 1024;
    unsigned short* w1_0t = p; p += 1024 * INDIM;
    unsigned short* w2_0t = p; p += INDIM * 1024;
    unsigned short* w1_1t = p; p += 1024 * INDIM;
    unsigned short* w2_1t = p; p += INDIM * 1024;
    unsigned short* w1_2t = p; p += 512 * INDIM;
    unsigned short* w2_2t = p; p += INDIM * 512;

    // 0) all weight transposes in ONE launch (z = weight index)
    transpose_all<<<dim3(26, 26, 6), 256, 0, stream>>>(
        w1_0, w1_0t, w2_0, w2_0t, w1_1, w1_1t, w2_1, w2_1t, w1_2, w1_2t, w2_2, w2_2t);

    // 1) embedding bag -> bf16 feat (windowed gather, 4 bags/wave)
    embed_pool<<<BATCH * FEATS / (4 * BPW), 256, 0, stream>>>(x, emb, feat);

    // 2) residual blocks (round-0 proven GEMM config)
    gemm_bf16<<<dim3(1024/128, BATCH/128), 512, 0, stream>>>(
        feat, w1_0t, b1_0, nullptr, h, BATCH, 1024, INDIM, 1);
    gemm_bf16<<<dim3(INDIM/128, BATCH/128), 512, 0, stream>>>(
        h, w2_0t, b2_0, feat, feat, BATCH, INDIM, 1024, 1);
    gemm_bf16<<<dim3(1024/128, BATCH/128), 512, 0, stream>>>(
        feat, w1_1t, b1_1, nullptr, h, BATCH, 1024, INDIM, 1);
    gemm_bf16<<<dim3(INDIM/128, BATCH/128), 512, 0, stream>>>(
        h, w2_1t, b2_1, feat, feat, BATCH, INDIM, 1024, 1);
    gemm_bf16<<<dim3(512/128, BATCH/128), 512, 0, stream>>>(
        feat, w1_2t, b1_2, nullptr, h, BATCH, 512, INDIM, 1);
    gemm_bf16<<<dim3(INDIM/128, BATCH/128), 512, 0, stream>>>(
        h, w2_2t, b2_2, feat, feat, BATCH, INDIM, 512, 1);

    // 3) head
    final_head<<<BATCH / 4, 256, 0, stream>>>(feat, linw, linb, out);
}

// Round 5
// 639.059 us; speedup vs baseline: 2.3661x; 1.1939x over previous
//
#include <hip/hip_runtime.h>

// Problem constants
#define BATCH 4096
#define FEATS 26
#define BAG   8
#define EDIM  64
#define INDIM 1664   // 26*64

typedef short bf16x8 __attribute__((ext_vector_type(8)));
typedef float f32x4  __attribute__((ext_vector_type(4)));
typedef unsigned short u16x8 __attribute__((ext_vector_type(8)));

__device__ __forceinline__ unsigned short f2bf(float f) {
    unsigned u = __float_as_uint(f);
    unsigned r = (u + 0x7FFFu + ((u >> 16) & 1u)) >> 16;
    return (unsigned short)r;
}
__device__ __forceinline__ float bf2f(unsigned short h) {
    return __uint_as_float((unsigned)h << 16);
}
// async global->LDS, 16B per lane. HW dst = wave-uniform base + lane*16.
__device__ __forceinline__ void async_cp16(const void* g, void* lds_base_uniform) {
    __builtin_amdgcn_global_load_lds(
        (const __attribute__((address_space(1))) unsigned int*)g,
        (__attribute__((address_space(3))) unsigned int*)lds_base_uniform,
        16, 0, 0);
}
// s_waitcnt with only vmcnt constrained (lgkm=15, exp=7 i.e. no wait)
#define WAITCNT_VM(n) __builtin_amdgcn_s_waitcnt(0x0F70 | (n))

// ---------------- batched weight transpose + fp32->bf16 (1 launch, 6 weights) ----
__global__ __launch_bounds__(256) void transpose_all(
    const float* __restrict__ w10, unsigned short* __restrict__ o10,
    const float* __restrict__ w20, unsigned short* __restrict__ o20,
    const float* __restrict__ w11, unsigned short* __restrict__ o11,
    const float* __restrict__ w21, unsigned short* __restrict__ o21,
    const float* __restrict__ w12, unsigned short* __restrict__ o12,
    const float* __restrict__ w22, unsigned short* __restrict__ o22)
{
    const float* in; unsigned short* out; int R, C;
    switch (blockIdx.z) {
        case 0:  in = w10; out = o10; R = INDIM; C = 1024;  break;
        case 1:  in = w20; out = o20; R = 1024;  C = INDIM; break;
        case 2:  in = w11; out = o11; R = INDIM; C = 1024;  break;
        case 3:  in = w21; out = o21; R = 1024;  C = INDIM; break;
        case 4:  in = w12; out = o12; R = INDIM; C = 512;   break;
        default: in = w22; out = o22; R = 512;   C = INDIM; break;
    }
    const int c0 = blockIdx.x * 64, r0 = blockIdx.y * 64;
    if (c0 >= C || r0 >= R) return;

    __shared__ unsigned short tile[64][65];
    const int t = threadIdx.x;
    const int tc = t & 63, tr = t >> 6;
#pragma unroll
    for (int i = 0; i < 16; ++i) {
        int r = tr + i * 4;
        tile[r][tc] = f2bf(in[(long long)(r0 + r) * C + c0 + tc]);
    }
    __syncthreads();
    const int wr = t >> 3, wc = t & 7;
#pragma unroll
    for (int half = 0; half < 2; ++half) {
        int row = wr + half * 32;
        u16x8 v;
#pragma unroll
        for (int j = 0; j < 8; ++j) v[j] = tile[wc * 8 + j][row];
        *(u16x8*)(out + (long long)(c0 + row) * R + r0 + wc * 8) = v;
    }
}

// ---------------- embedding bag: windowed gather + register sum-pool -> bf16 ----
// Each wave owns BPW=4 bags (32 ids, register accumulators, NO atomics, writes
// only 4x128B). Gathers are issued window-by-window over the table:
// NWIN=4 windows of 64MB (off>>24). Per wave per window ~8 independent
// predicated loads -> MLP ~= 8 (round-0 level) WHILE resident waves sweep
// windows near-lockstep, keeping the active table footprint ~64-128MB
// (L3-resident) so duplicate ids hit cache and DRAM sees ~57%-dense sweeps.
// (Round-4's NWIN=31 had the locality but only ~1 load/window -> latency-bound.)
#define BPW 4
#define NWIN 4
__global__ __launch_bounds__(256) void embed_pool(
    const int* __restrict__ x, const float* __restrict__ emb,
    unsigned short* __restrict__ feat)
{
    const int wave = threadIdx.x >> 6, lane = threadIdx.x & 63;
    const int bag0 = (blockIdx.x * 4 + wave) * BPW;
    const float* embl = emb + lane;

    // element offsets id*64 fit u32 (max 6.4e7 < 2^26); window = off >> 24
    unsigned off[BPW][BAG];
#pragma unroll
    for (int g = 0; g < BPW; ++g)
#pragma unroll
        for (int l = 0; l < BAG; ++l)
            off[g][l] = (unsigned)x[(bag0 + g) * BAG + l] * (unsigned)EDIM;

    float s[BPW] = {};
#pragma unroll 1
    for (unsigned w = 0; w < NWIN; ++w) {
#pragma unroll
        for (int g = 0; g < BPW; ++g)
#pragma unroll
            for (int l = 0; l < BAG; ++l)
                if ((off[g][l] >> 24) == w)
                    s[g] += embl[off[g][l]];
    }
#pragma unroll
    for (int g = 0; g < BPW; ++g) {
        int bag = bag0 + g;
        int b = bag / FEATS, f = bag - b * FEATS;
        feat[(long long)b * INDIM + f * EDIM + lane] = f2bf(s[g]);
    }
}

// ------------- bf16 MFMA GEMM, 128x128 tile, BK=32, 4-deep async pipeline ----
// (round-0 proven config) 512 threads = 8 waves; wave tile 64x32.
// LDS: 4 buffers x (A 8KB + B 8KB) = 64 KB. One s_barrier per K-iter, fine vmcnt.
// XOR swizzle: LDS slot (row, s) holds global k-chunk s ^ ((row>>1)&3)  (16B chunks).
#define NBUF 4
__global__ __launch_bounds__(512) void gemm_bf16(
    const unsigned short* __restrict__ A, const unsigned short* __restrict__ Wt,
    const float* __restrict__ bias, const unsigned short* __restrict__ res,
    unsigned short* __restrict__ out, int M, int N, int K, int do_relu)
{
    __shared__ unsigned short As[NBUF * 128 * 32];
    __shared__ unsigned short Bs[NBUF * 128 * 32];

    const int t    = threadIdx.x;
    const int bCol = blockIdx.x * 128;
    const int bRow = blockIdx.y * 128;
    const int wave = t >> 6, lane = t & 63;
    const int wm = wave & 1, wn = wave >> 1;       // wn in 0..3
    const int lm = lane & 15, quad = lane >> 4;

    const int srow = lane >> 2;
    const int sq   = (lane & 3) ^ ((lane >> 3) & 3);
    const unsigned short* Ag = A  + (long long)(bRow + wave * 16 + srow) * K + sq * 8;
    const unsigned short* Bg = Wt + (long long)(bCol + wave * 16 + srow) * K + sq * 8;
    unsigned short* AsW = As + wave * 512;   // + buf*4096
    unsigned short* BsW = Bs + wave * 512;

    const int T = K / 32;
    f32x4 acc[4][2] = {};
    const int slot = (quad ^ ((lm >> 1) & 3)) * 8;

#define ISSUE(tile_)  do { int _b = (tile_) & (NBUF - 1);                         \
        async_cp16(Ag + (long long)(tile_) * 32, AsW + _b * 4096);                \
        async_cp16(Bg + (long long)(tile_) * 32, BsW + _b * 4096); } while (0)

#define COMPUTE(tile_) do { int _b = (tile_) & (NBUF - 1);                        \
        const unsigned short* _a = As + _b * 4096;                                \
        const unsigned short* _bp = Bs + _b * 4096;                               \
        bf16x8 af[4], bf[2];                                                      \
        _Pragma("unroll")                                                         \
        for (int i = 0; i < 4; ++i)                                               \
            af[i] = *(const bf16x8*)&_a[(wm * 64 + i * 16 + lm) * 32 + slot];     \
        _Pragma("unroll")                                                         \
        for (int j = 0; j < 2; ++j)                                               \
            bf[j] = *(const bf16x8*)&_bp[(wn * 32 + j * 16 + lm) * 32 + slot];    \
        _Pragma("unroll")                                                         \
        for (int i = 0; i < 4; ++i)                                               \
            _Pragma("unroll")                                                     \
            for (int j = 0; j < 2; ++j)                                           \
                acc[i][j] = __builtin_amdgcn_mfma_f32_16x16x32_bf16(              \
                    af[i], bf[j], acc[i][j], 0, 0, 0); } while (0)

    ISSUE(0);
    ISSUE(1);
    for (int tt = 0; tt < T - 2; ++tt) {
        ISSUE(tt + 2);                 // lands in buf[(tt+2)&3] = buf[(tt-2)&3]: reads done
        WAITCNT_VM(4);                 // tile tt's 2 loads complete (t+1,t+2 still in flight)
        asm volatile("" ::: "memory");
        __builtin_amdgcn_s_barrier();
        asm volatile("" ::: "memory");
        COMPUTE(tt);
    }
    WAITCNT_VM(2);
    asm volatile("" ::: "memory");
    __builtin_amdgcn_s_barrier();
    asm volatile("" ::: "memory");
    COMPUTE(T - 2);
    WAITCNT_VM(0);
    asm volatile("" ::: "memory");
    __builtin_amdgcn_s_barrier();
    asm volatile("" ::: "memory");
    COMPUTE(T - 1);

    // ---- epilogue: bias (+res) (+relu), bf16 out ----
#pragma unroll
    for (int i = 0; i < 4; ++i) {
#pragma unroll
        for (int j = 0; j < 2; ++j) {
            int col = bCol + wn * 32 + j * 16 + lm;
            float bv = bias[col];
#pragma unroll
            for (int r = 0; r < 4; ++r) {
                int row = bRow + wm * 64 + i * 16 + quad * 4 + r;
                float v = acc[i][j][r] + bv;
                if (res) v += bf2f(res[(long long)row * N + col]);
                if (do_relu) v = fmaxf(v, 0.f);
                out[(long long)row * N + col] = f2bf(v);
            }
        }
    }
#undef ISSUE
#undef COMPUTE
}

// ---------------- final linear + sigmoid ----------------
__global__ __launch_bounds__(256) void final_head(
    const unsigned short* __restrict__ feat, const float* __restrict__ lin_w,
    const float* __restrict__ lin_b, float* __restrict__ out)
{
    int row  = blockIdx.x * 4 + (threadIdx.x >> 6);
    int lane = threadIdx.x & 63;
    const unsigned short* fr = feat + (long long)row * INDIM;
    float s = 0.f;
#pragma unroll
    for (int it = 0; it < INDIM / 64; ++it)
        s += bf2f(fr[it * 64 + lane]) * lin_w[it * 64 + lane];
#pragma unroll
    for (int off = 32; off; off >>= 1)
        s += __shfl_down(s, off, 64);
    if (lane == 0)
        out[row] = 1.f / (1.f + __expf(-(s + lin_b[0])));
}

extern "C" void kernel_launch(void* const* d_in, const int* in_sizes, int n_in,
                              void* d_out, int out_size, void* d_ws, size_t ws_size,
                              hipStream_t stream) {
    const int*   x    = (const int*)  d_in[0];
    const float* emb  = (const float*)d_in[1];
    const float* w1_0 = (const float*)d_in[2];
    const float* b1_0 = (const float*)d_in[3];
    const float* w2_0 = (const float*)d_in[4];
    const float* b2_0 = (const float*)d_in[5];
    const float* w1_1 = (const float*)d_in[6];
    const float* b1_1 = (const float*)d_in[7];
    const float* w2_1 = (const float*)d_in[8];
    const float* b2_1 = (const float*)d_in[9];
    const float* w1_2 = (const float*)d_in[10];
    const float* b1_2 = (const float*)d_in[11];
    const float* w2_2 = (const float*)d_in[12];
    const float* b2_2 = (const float*)d_in[13];
    const float* linw = (const float*)d_in[14];
    const float* linb = (const float*)d_in[15];
    float* out = (float*)d_out;

    // ws layout (bf16 elements)
    unsigned short* feat = (unsigned short*)d_ws;            // [4096,1664]
    unsigned short* h    = feat + (long long)BATCH * INDIM;  // [4096,1024]
    unsigned short* p    = h + (long long)BATCH * 1024;
    unsigned short* w1_0t = p; p += 1024 * INDIM;
    unsigned short* w2_0t = p; p += INDIM * 1024;
    unsigned short* w1_1t = p; p += 1024 * INDIM;
    unsigned short* w2_1t = p; p += INDIM * 1024;
    unsigned short* w1_2t = p; p += 512 * INDIM;
    unsigned short* w2_2t = p; p += INDIM * 512;

    // 0) all weight transposes in ONE launch (z = weight index)
    transpose_all<<<dim3(26, 26, 6), 256, 0, stream>>>(
        w1_0, w1_0t, w2_0, w2_0t, w1_1, w1_1t, w2_1, w2_1t, w1_2, w1_2t, w2_2, w2_2t);

    // 1) embedding bag -> bf16 feat (4-window gather, 4 bags/wave)
    embed_pool<<<BATCH * FEATS / (4 * BPW), 256, 0, stream>>>(x, emb, feat);

    // 2) residual blocks (round-0 proven GEMM config)
    gemm_bf16<<<dim3(1024/128, BATCH/128), 512, 0, stream>>>(
        feat, w1_0t, b1_0, nullptr, h, BATCH, 1024, INDIM, 1);
    gemm_bf16<<<dim3(INDIM/128, BATCH/128), 512, 0, stream>>>(
        h, w2_0t, b2_0, feat, feat, BATCH, INDIM, 1024, 1);
    gemm_bf16<<<dim3(1024/128, BATCH/128), 512, 0, stream>>>(
        feat, w1_1t, b1_1, nullptr, h, BATCH, 1024, INDIM, 1);
    gemm_bf16<<<dim3(INDIM/128, BATCH/128), 512, 0, stream>>>(
        h, w2_1t, b2_1, feat, feat, BATCH, INDIM, 1024, 1);
    gemm_bf16<<<dim3(512/128, BATCH/128), 512, 0, stream>>>(
        feat, w1_2t, b1_2, nullptr, h, BATCH, 512, INDIM, 1);
    gemm_bf16<<<dim3(INDIM/128, BATCH/128), 512, 0, stream>>>(
        h, w2_2t, b2_2, feat, feat, BATCH, INDIM, 512, 1);

    // 3) head
    final_head<<<BATCH / 4, 256, 0, stream>>>(feat, linw, linb, out);
}

// Round 6
// 602.981 us; speedup vs baseline: 2.5077x; 1.0598x over previous
//
#include <hip/hip_runtime.h>

// Problem constants
#define BATCH 4096
#define FEATS 26
#define BAG   8
#define EDIM  64
#define INDIM 1664   // 26*64

typedef short bf16x8 __attribute__((ext_vector_type(8)));
typedef float f32x4  __attribute__((ext_vector_type(4)));
typedef unsigned short u16x8 __attribute__((ext_vector_type(8)));

__device__ __forceinline__ unsigned short f2bf(float f) {
    unsigned u = __float_as_uint(f);
    unsigned r = (u + 0x7FFFu + ((u >> 16) & 1u)) >> 16;
    return (unsigned short)r;
}
__device__ __forceinline__ float bf2f(unsigned short h) {
    return __uint_as_float((unsigned)h << 16);
}
// async global->LDS, 16B per lane. HW dst = wave-uniform base + lane*16.
__device__ __forceinline__ void async_cp16(const void* g, void* lds_base_uniform) {
    __builtin_amdgcn_global_load_lds(
        (const __attribute__((address_space(1))) unsigned int*)g,
        (__attribute__((address_space(3))) unsigned int*)lds_base_uniform,
        16, 0, 0);
}
// s_waitcnt with only vmcnt constrained (lgkm=15, exp=7 i.e. no wait)
#define WAITCNT_VM(n) __builtin_amdgcn_s_waitcnt(0x0F70 | (n))

// ---------------- batched weight transpose + fp32->bf16 (1 launch, 6 weights) ----
__global__ __launch_bounds__(256) void transpose_all(
    const float* __restrict__ w10, unsigned short* __restrict__ o10,
    const float* __restrict__ w20, unsigned short* __restrict__ o20,
    const float* __restrict__ w11, unsigned short* __restrict__ o11,
    const float* __restrict__ w21, unsigned short* __restrict__ o21,
    const float* __restrict__ w12, unsigned short* __restrict__ o12,
    const float* __restrict__ w22, unsigned short* __restrict__ o22)
{
    const float* in; unsigned short* out; int R, C;
    switch (blockIdx.z) {
        case 0:  in = w10; out = o10; R = INDIM; C = 1024;  break;
        case 1:  in = w20; out = o20; R = 1024;  C = INDIM; break;
        case 2:  in = w11; out = o11; R = INDIM; C = 1024;  break;
        case 3:  in = w21; out = o21; R = 1024;  C = INDIM; break;
        case 4:  in = w12; out = o12; R = INDIM; C = 512;   break;
        default: in = w22; out = o22; R = 512;   C = INDIM; break;
    }
    const int c0 = blockIdx.x * 64, r0 = blockIdx.y * 64;
    if (c0 >= C || r0 >= R) return;

    __shared__ unsigned short tile[64][65];
    const int t = threadIdx.x;
    const int tc = t & 63, tr = t >> 6;
#pragma unroll
    for (int i = 0; i < 16; ++i) {
        int r = tr + i * 4;
        tile[r][tc] = f2bf(in[(long long)(r0 + r) * C + c0 + tc]);
    }
    __syncthreads();
    const int wr = t >> 3, wc = t & 7;
#pragma unroll
    for (int half = 0; half < 2; ++half) {
        int row = wr + half * 32;
        u16x8 v;
#pragma unroll
        for (int j = 0; j < 8; ++j) v[j] = tile[wc * 8 + j][row];
        *(u16x8*)(out + (long long)(c0 + row) * R + r0 + wc * 8) = v;
    }
}

// ---------------- embedding bag (round-0 form, measured ~90us) ----------------
__global__ __launch_bounds__(256) void embed_pool(
    const int* __restrict__ x, const float* __restrict__ emb,
    unsigned short* __restrict__ feat)
{
    int bag  = blockIdx.x * 4 + (threadIdx.x >> 6);
    int lane = threadIdx.x & 63;
    int b = bag / FEATS;
    int f = bag - b * FEATS;
    const int* xs = x + (long long)bag * BAG;
    float s = 0.f;
#pragma unroll
    for (int l = 0; l < BAG; ++l) {
        int id = xs[l];
        s += emb[(long long)id * EDIM + lane];
    }
    feat[(long long)b * INDIM + f * EDIM + lane] = f2bf(s);
}

// ------------- bf16 MFMA GEMM, m97-verified structure -------------
// 128xBN tile, BK=32, 256 threads = 4 waves, wave tile 64x(BN/2) -> 16 MFMA :
// 8 ds_read per K-iter. NBUF=2 (LDS 32KB for BN=128) -> 3 blocks/CU co-resident
// (cross-block wave overlap hides the drain-barrier stall, m114 mechanism).
// Loop: ISSUE(t+1) -> COMPUTE(t) -> vmcnt(0) -> barrier  (no WAR race: buffer
// (t+1)&1 was last read in COMPUTE(t-1), one full barrier ago).
// XOR swizzle: LDS slot (row, s) holds global k-chunk s ^ ((row>>1)&3) (16B chunks).
#define NBUF 2
template<int BN>
__global__ __launch_bounds__(256, 3) void gemm_bf16(
    const unsigned short* __restrict__ A, const unsigned short* __restrict__ Wt,
    const float* __restrict__ bias, const unsigned short* __restrict__ res,
    unsigned short* __restrict__ out, int M, int N, int K, int do_relu)
{
    constexpr int JN = BN / 32;          // col fragments per wave (4 or 2)

    __shared__ unsigned short As[NBUF * 128 * 32];
    __shared__ unsigned short Bs[NBUF * BN * 32];

    const int t    = threadIdx.x;
    const int bCol = blockIdx.x * BN;
    const int bRow = blockIdx.y * 128;
    const int wave = t >> 6, lane = t & 63;
    const int wm = wave & 1, wn = wave >> 1;       // 2x2 wave grid
    const int lm = lane & 15, quad = lane >> 4;

    // staging: lane l -> row +l/4, global k-chunk (l&3)^((l>>3)&3) (inv swizzle)
    const int srow = lane >> 2;
    const int sq   = (lane & 3) ^ ((lane >> 3) & 3);
    const int slot = (quad ^ ((lm >> 1) & 3)) * 8;

    // A: 128 rows -> 2 instrs/wave (rows wave*32+srow, +16)
    const unsigned short* Ag  = A + (long long)(bRow + wave * 32 + srow) * K + sq * 8;
    const unsigned short* Ag2 = Ag + 16 * (long long)K;
    // B: BN rows -> 2 instrs/wave (BN=128) or 1 (BN=64)
    const unsigned short* Bg  = Wt + (long long)(bCol + (BN == 128 ? wave * 32 : wave * 16) + srow) * K + sq * 8;
    const unsigned short* Bg2 = Bg + 16 * (long long)K;
    unsigned short* AsW = As + wave * 1024;                      // + buf*4096
    unsigned short* BsW = Bs + wave * (BN == 128 ? 1024 : 512);  // + buf*(BN*32)

    const int T = K / 32;
    f32x4 acc[4][JN] = {};

#define ISSUE(t_)  do { int _b = (t_) & 1;                                        \
        async_cp16(Ag  + (t_) * 32, AsW + _b * 4096);                             \
        async_cp16(Ag2 + (t_) * 32, AsW + _b * 4096 + 512);                       \
        async_cp16(Bg  + (t_) * 32, BsW + _b * (BN * 32));                        \
        if constexpr (BN == 128)                                                  \
            async_cp16(Bg2 + (t_) * 32, BsW + _b * (BN * 32) + 512);              \
    } while (0)

#define COMPUTE(t_) do { int _b = (t_) & 1;                                       \
        const unsigned short* _a  = As + _b * 4096;                               \
        const unsigned short* _bp = Bs + _b * (BN * 32);                          \
        bf16x8 af[4], bfr[JN];                                                    \
        _Pragma("unroll")                                                         \
        for (int i = 0; i < 4; ++i)                                               \
            af[i] = *(const bf16x8*)&_a[(wm * 64 + i * 16 + lm) * 32 + slot];     \
        _Pragma("unroll")                                                         \
        for (int j = 0; j < JN; ++j)                                              \
            bfr[j] = *(const bf16x8*)&_bp[(wn * (BN / 2) + j * 16 + lm) * 32 + slot]; \
        _Pragma("unroll")                                                         \
        for (int i = 0; i < 4; ++i)                                               \
            _Pragma("unroll")                                                     \
            for (int j = 0; j < JN; ++j)                                          \
                acc[i][j] = __builtin_amdgcn_mfma_f32_16x16x32_bf16(              \
                    af[i], bfr[j], acc[i][j], 0, 0, 0); } while (0)

    ISSUE(0);
    WAITCNT_VM(0);
    asm volatile("" ::: "memory");
    __builtin_amdgcn_s_barrier();
    asm volatile("" ::: "memory");
    for (int tt = 0; tt < T; ++tt) {
        if (tt + 1 < T) ISSUE(tt + 1);
        COMPUTE(tt);
        WAITCNT_VM(0);
        asm volatile("" ::: "memory");
        __builtin_amdgcn_s_barrier();
        asm volatile("" ::: "memory");
    }

    // ---- epilogue: bias (+res) (+relu), bf16 out ----
#pragma unroll
    for (int i = 0; i < 4; ++i) {
#pragma unroll
        for (int j = 0; j < JN; ++j) {
            int col = bCol + wn * (BN / 2) + j * 16 + lm;
            float bv = bias[col];
#pragma unroll
            for (int r = 0; r < 4; ++r) {
                int row = bRow + wm * 64 + i * 16 + quad * 4 + r;
                float v = acc[i][j][r] + bv;
                if (res) v += bf2f(res[(long long)row * N + col]);
                if (do_relu) v = fmaxf(v, 0.f);
                out[(long long)row * N + col] = f2bf(v);
            }
        }
    }
#undef ISSUE
#undef COMPUTE
}

// ---------------- final linear + sigmoid ----------------
__global__ __launch_bounds__(256) void final_head(
    const unsigned short* __restrict__ feat, const float* __restrict__ lin_w,
    const float* __restrict__ lin_b, float* __restrict__ out)
{
    int row  = blockIdx.x * 4 + (threadIdx.x >> 6);
    int lane = threadIdx.x & 63;
    const unsigned short* fr = feat + (long long)row * INDIM;
    float s = 0.f;
#pragma unroll
    for (int it = 0; it < INDIM / 64; ++it)
        s += bf2f(fr[it * 64 + lane]) * lin_w[it * 64 + lane];
#pragma unroll
    for (int off = 32; off; off >>= 1)
        s += __shfl_down(s, off, 64);
    if (lane == 0)
        out[row] = 1.f / (1.f + __expf(-(s + lin_b[0])));
}

extern "C" void kernel_launch(void* const* d_in, const int* in_sizes, int n_in,
                              void* d_out, int out_size, void* d_ws, size_t ws_size,
                              hipStream_t stream) {
    const int*   x    = (const int*)  d_in[0];
    const float* emb  = (const float*)d_in[1];
    const float* w1_0 = (const float*)d_in[2];
    const float* b1_0 = (const float*)d_in[3];
    const float* w2_0 = (const float*)d_in[4];
    const float* b2_0 = (const float*)d_in[5];
    const float* w1_1 = (const float*)d_in[6];
    const float* b1_1 = (const float*)d_in[7];
    const float* w2_1 = (const float*)d_in[8];
    const float* b2_1 = (const float*)d_in[9];
    const float* w1_2 = (const float*)d_in[10];
    const float* b1_2 = (const float*)d_in[11];
    const float* w2_2 = (const float*)d_in[12];
    const float* b2_2 = (const float*)d_in[13];
    const float* linw = (const float*)d_in[14];
    const float* linb = (const float*)d_in[15];
    float* out = (float*)d_out;

    // ws layout (bf16 elements)
    unsigned short* feat = (unsigned short*)d_ws;            // [4096,1664]
    unsigned short* h    = feat + (long long)BATCH * INDIM;  // [4096,1024]
    unsigned short* p    = h + (long long)BATCH * 1024;
    unsigned short* w1_0t = p; p += 1024 * INDIM;
    unsigned short* w2_0t = p; p += INDIM * 1024;
    unsigned short* w1_1t = p; p += 1024 * INDIM;
    unsigned short* w2_1t = p; p += INDIM * 1024;
    unsigned short* w1_2t = p; p += 512 * INDIM;
    unsigned short* w2_2t = p; p += INDIM * 512;

    // 0) all weight transposes in ONE launch (z = weight index)
    transpose_all<<<dim3(26, 26, 6), 256, 0, stream>>>(
        w1_0, w1_0t, w2_0, w2_0t, w1_1, w1_1t, w2_1, w2_1t, w1_2, w1_2t, w2_2, w2_2t);

    // 1) embedding bag -> bf16 feat (round-0 form)
    embed_pool<<<BATCH * FEATS / 4, 256, 0, stream>>>(x, emb, feat);

    // 2) residual blocks (m97-structure GEMM, 3 blocks/CU)
    gemm_bf16<128><<<dim3(1024/128, BATCH/128), 256, 0, stream>>>(
        feat, w1_0t, b1_0, nullptr, h, BATCH, 1024, INDIM, 1);
    gemm_bf16<128><<<dim3(INDIM/128, BATCH/128), 256, 0, stream>>>(
        h, w2_0t, b2_0, feat, feat, BATCH, INDIM, 1024, 1);
    gemm_bf16<128><<<dim3(1024/128, BATCH/128), 256, 0, stream>>>(
        feat, w1_1t, b1_1, nullptr, h, BATCH, 1024, INDIM, 1);
    gemm_bf16<128><<<dim3(INDIM/128, BATCH/128), 256, 0, stream>>>(
        h, w2_1t, b2_1, feat, feat, BATCH, INDIM, 1024, 1);
    gemm_bf16<64><<<dim3(512/64, BATCH/128), 256, 0, stream>>>(
        feat, w1_2t, b1_2, nullptr, h, BATCH, 512, INDIM, 1);
    gemm_bf16<128><<<dim3(INDIM/128, BATCH/128), 256, 0, stream>>>(
        h, w2_2t, b2_2, feat, feat, BATCH, INDIM, 512, 1);

    // 3) head
    final_head<<<BATCH / 4, 256, 0, stream>>>(feat, linw, linb, out);
}

// Round 7
// 534.708 us; speedup vs baseline: 2.8279x; 1.1277x over previous
//
#include <hip/hip_runtime.h>

// Problem constants
#define BATCH 4096
#define FEATS 26
#define BAG   8
#define EDIM  64
#define INDIM 1664   // 26*64

typedef short bf16x8 __attribute__((ext_vector_type(8)));
typedef float f32x4  __attribute__((ext_vector_type(4)));
typedef unsigned short u16x8 __attribute__((ext_vector_type(8)));

__device__ __forceinline__ unsigned short f2bf(float f) {
    unsigned u = __float_as_uint(f);
    unsigned r = (u + 0x7FFFu + ((u >> 16) & 1u)) >> 16;
    return (unsigned short)r;
}
__device__ __forceinline__ float bf2f(unsigned short h) {
    return __uint_as_float((unsigned)h << 16);
}
// async global->LDS, 16B per lane. HW dst = wave-uniform base + lane*16.
__device__ __forceinline__ void async_cp16(const void* g, void* lds_base_uniform) {
    __builtin_amdgcn_global_load_lds(
        (const __attribute__((address_space(1))) unsigned int*)g,
        (__attribute__((address_space(3))) unsigned int*)lds_base_uniform,
        16, 0, 0);
}
// s_waitcnt with only vmcnt constrained (lgkm=15, exp=7 i.e. no wait)
#define WAITCNT_VM(n) __builtin_amdgcn_s_waitcnt(0x0F70 | (n))

// ---------------- batched weight transpose + fp32->bf16 (1 launch, 6 weights) ----
__global__ __launch_bounds__(256) void transpose_all(
    const float* __restrict__ w10, unsigned short* __restrict__ o10,
    const float* __restrict__ w20, unsigned short* __restrict__ o20,
    const float* __restrict__ w11, unsigned short* __restrict__ o11,
    const float* __restrict__ w21, unsigned short* __restrict__ o21,
    const float* __restrict__ w12, unsigned short* __restrict__ o12,
    const float* __restrict__ w22, unsigned short* __restrict__ o22)
{
    const float* in; unsigned short* out; int R, C;
    switch (blockIdx.z) {
        case 0:  in = w10; out = o10; R = INDIM; C = 1024;  break;
        case 1:  in = w20; out = o20; R = 1024;  C = INDIM; break;
        case 2:  in = w11; out = o11; R = INDIM; C = 1024;  break;
        case 3:  in = w21; out = o21; R = 1024;  C = INDIM; break;
        case 4:  in = w12; out = o12; R = INDIM; C = 512;   break;
        default: in = w22; out = o22; R = 512;   C = INDIM; break;
    }
    const int c0 = blockIdx.x * 64, r0 = blockIdx.y * 64;
    if (c0 >= C || r0 >= R) return;

    __shared__ unsigned short tile[64][65];
    const int t = threadIdx.x;
    const int tc = t & 63, tr = t >> 6;
#pragma unroll
    for (int i = 0; i < 16; ++i) {
        int r = tr + i * 4;
        tile[r][tc] = f2bf(in[(long long)(r0 + r) * C + c0 + tc]);
    }
    __syncthreads();
    const int wr = t >> 3, wc = t & 7;
#pragma unroll
    for (int half = 0; half < 2; ++half) {
        int row = wr + half * 32;
        u16x8 v;
#pragma unroll
        for (int j = 0; j < 8; ++j) v[j] = tile[wc * 8 + j][row];
        *(u16x8*)(out + (long long)(c0 + row) * R + r0 + wc * 8) = v;
    }
}

// ---------------- embedding bag (round-0 form) ----------------
__global__ __launch_bounds__(256) void embed_pool(
    const int* __restrict__ x, const float* __restrict__ emb,
    unsigned short* __restrict__ feat)
{
    int bag  = blockIdx.x * 4 + (threadIdx.x >> 6);
    int lane = threadIdx.x & 63;
    int b = bag / FEATS;
    int f = bag - b * FEATS;
    const int* xs = x + (long long)bag * BAG;
    float s = 0.f;
#pragma unroll
    for (int l = 0; l < BAG; ++l) {
        int id = xs[l];
        s += emb[(long long)id * EDIM + lane];
    }
    feat[(long long)b * INDIM + f * EDIM + lane] = f2bf(s);
}

// ------------- bf16 MFMA GEMM (round-0 structure) + XCD-grouping swizzle ----
// 128x128 tile, BK=32, 512 threads = 8 waves, wave tile 64x32, NBUF=4,
// counted vmcnt (loads stay in flight across barriers).
// Tile swizzle: linearize col-fastest, chunk q=nwg/8 consecutive tiles per XCD
// (dispatch round-robins blocks across XCDs, so lin&7 = XCD). Each XCD then
// owns 4 contiguous row-panels x all col-tiles: working set = 4 A-panels
// (1.7MB) + B (3.4MB) ~= L2-resident -> A fetched ~once, B ~once per XCD
// (was: A x8, B x32 from L3/HBM = 218MB staged per GEMM, traffic-bound).
// XOR swizzle: LDS slot (row, s) holds global k-chunk s ^ ((row>>1)&3) (16B chunks).
#define NBUF 4
__global__ __launch_bounds__(512) void gemm_bf16(
    const unsigned short* __restrict__ A, const unsigned short* __restrict__ Wt,
    const float* __restrict__ bias, const unsigned short* __restrict__ res,
    unsigned short* __restrict__ out, int M, int N, int K, int do_relu)
{
    __shared__ unsigned short As[NBUF * 128 * 32];
    __shared__ unsigned short Bs[NBUF * 128 * 32];

    const int t    = threadIdx.x;
    // ---- XCD-grouping tile swizzle (nwg % 8 == 0 for all grids here) ----
    const int nxg = gridDim.x;
    const int lin = blockIdx.y * nxg + blockIdx.x;
    const int q   = (nxg * gridDim.y) >> 3;
    const int tile = (lin & 7) * q + (lin >> 3);
    const int ty  = tile / nxg;
    const int bCol = (tile - ty * nxg) * 128;
    const int bRow = ty * 128;

    const int wave = t >> 6, lane = t & 63;
    const int wm = wave & 1, wn = wave >> 1;       // wn in 0..3
    const int lm = lane & 15, quad = lane >> 4;

    const int srow = lane >> 2;
    const int sq   = (lane & 3) ^ ((lane >> 3) & 3);
    const unsigned short* Ag = A  + (long long)(bRow + wave * 16 + srow) * K + sq * 8;
    const unsigned short* Bg = Wt + (long long)(bCol + wave * 16 + srow) * K + sq * 8;
    unsigned short* AsW = As + wave * 512;   // + buf*4096
    unsigned short* BsW = Bs + wave * 512;

    const int T = K / 32;
    f32x4 acc[4][2] = {};
    const int slot = (quad ^ ((lm >> 1) & 3)) * 8;

#define ISSUE(tile_)  do { int _b = (tile_) & (NBUF - 1);                         \
        async_cp16(Ag + (long long)(tile_) * 32, AsW + _b * 4096);                \
        async_cp16(Bg + (long long)(tile_) * 32, BsW + _b * 4096); } while (0)

#define COMPUTE(tile_) do { int _b = (tile_) & (NBUF - 1);                        \
        const unsigned short* _a = As + _b * 4096;                                \
        const unsigned short* _bp = Bs + _b * 4096;                               \
        bf16x8 af[4], bf[2];                                                      \
        _Pragma("unroll")                                                         \
        for (int i = 0; i < 4; ++i)                                               \
            af[i] = *(const bf16x8*)&_a[(wm * 64 + i * 16 + lm) * 32 + slot];     \
        _Pragma("unroll")                                                         \
        for (int j = 0; j < 2; ++j)                                               \
            bf[j] = *(const bf16x8*)&_bp[(wn * 32 + j * 16 + lm) * 32 + slot];    \
        _Pragma("unroll")                                                         \
        for (int i = 0; i < 4; ++i)                                               \
            _Pragma("unroll")                                                     \
            for (int j = 0; j < 2; ++j)                                           \
                acc[i][j] = __builtin_amdgcn_mfma_f32_16x16x32_bf16(              \
                    af[i], bf[j], acc[i][j], 0, 0, 0); } while (0)

    ISSUE(0);
    ISSUE(1);
    for (int tt = 0; tt < T - 2; ++tt) {
        ISSUE(tt + 2);                 // lands in buf[(tt+2)&3] = buf[(tt-2)&3]: reads done
        WAITCNT_VM(4);                 // tile tt's 2 loads complete (t+1,t+2 still in flight)
        asm volatile("" ::: "memory");
        __builtin_amdgcn_s_barrier();
        asm volatile("" ::: "memory");
        COMPUTE(tt);
    }
    WAITCNT_VM(2);
    asm volatile("" ::: "memory");
    __builtin_amdgcn_s_barrier();
    asm volatile("" ::: "memory");
    COMPUTE(T - 2);
    WAITCNT_VM(0);
    asm volatile("" ::: "memory");
    __builtin_amdgcn_s_barrier();
    asm volatile("" ::: "memory");
    COMPUTE(T - 1);

    // ---- epilogue: bias (+res) (+relu), bf16 out ----
#pragma unroll
    for (int i = 0; i < 4; ++i) {
#pragma unroll
        for (int j = 0; j < 2; ++j) {
            int col = bCol + wn * 32 + j * 16 + lm;
            float bv = bias[col];
#pragma unroll
            for (int r = 0; r < 4; ++r) {
                int row = bRow + wm * 64 + i * 16 + quad * 4 + r;
                float v = acc[i][j][r] + bv;
                if (res) v += bf2f(res[(long long)row * N + col]);
                if (do_relu) v = fmaxf(v, 0.f);
                out[(long long)row * N + col] = f2bf(v);
            }
        }
    }
#undef ISSUE
#undef COMPUTE
}

// ---------------- final linear + sigmoid ----------------
__global__ __launch_bounds__(256) void final_head(
    const unsigned short* __restrict__ feat, const float* __restrict__ lin_w,
    const float* __restrict__ lin_b, float* __restrict__ out)
{
    int row  = blockIdx.x * 4 + (threadIdx.x >> 6);
    int lane = threadIdx.x & 63;
    const unsigned short* fr = feat + (long long)row * INDIM;
    float s = 0.f;
#pragma unroll
    for (int it = 0; it < INDIM / 64; ++it)
        s += bf2f(fr[it * 64 + lane]) * lin_w[it * 64 + lane];
#pragma unroll
    for (int off = 32; off; off >>= 1)
        s += __shfl_down(s, off, 64);
    if (lane == 0)
        out[row] = 1.f / (1.f + __expf(-(s + lin_b[0])));
}

extern "C" void kernel_launch(void* const* d_in, const int* in_sizes, int n_in,
                              void* d_out, int out_size, void* d_ws, size_t ws_size,
                              hipStream_t stream) {
    const int*   x    = (const int*)  d_in[0];
    const float* emb  = (const float*)d_in[1];
    const float* w1_0 = (const float*)d_in[2];
    const float* b1_0 = (const float*)d_in[3];
    const float* w2_0 = (const float*)d_in[4];
    const float* b2_0 = (const float*)d_in[5];
    const float* w1_1 = (const float*)d_in[6];
    const float* b1_1 = (const float*)d_in[7];
    const float* w2_1 = (const float*)d_in[8];
    const float* b2_1 = (const float*)d_in[9];
    const float* w1_2 = (const float*)d_in[10];
    const float* b1_2 = (const float*)d_in[11];
    const float* w2_2 = (const float*)d_in[12];
    const float* b2_2 = (const float*)d_in[13];
    const float* linw = (const float*)d_in[14];
    const float* linb = (const float*)d_in[15];
    float* out = (float*)d_out;

    // ws layout (bf16 elements)
    unsigned short* feat = (unsigned short*)d_ws;            // [4096,1664]
    unsigned short* h    = feat + (long long)BATCH * INDIM;  // [4096,1024]
    unsigned short* p    = h + (long long)BATCH * 1024;
    unsigned short* w1_0t = p; p += 1024 * INDIM;
    unsigned short* w2_0t = p; p += INDIM * 1024;
    unsigned short* w1_1t = p; p += 1024 * INDIM;
    unsigned short* w2_1t = p; p += INDIM * 1024;
    unsigned short* w1_2t = p; p += 512 * INDIM;
    unsigned short* w2_2t = p; p += INDIM * 512;

    // 0) all weight transposes in ONE launch (z = weight index)
    transpose_all<<<dim3(26, 26, 6), 256, 0, stream>>>(
        w1_0, w1_0t, w2_0, w2_0t, w1_1, w1_1t, w2_1, w2_1t, w1_2, w1_2t, w2_2, w2_2t);

    // 1) embedding bag -> bf16 feat
    embed_pool<<<BATCH * FEATS / 4, 256, 0, stream>>>(x, emb, feat);

    // 2) residual blocks (round-0 GEMM + XCD-grouping swizzle)
    gemm_bf16<<<dim3(1024/128, BATCH/128), 512, 0, stream>>>(
        feat, w1_0t, b1_0, nullptr, h, BATCH, 1024, INDIM, 1);
    gemm_bf16<<<dim3(INDIM/128, BATCH/128), 512, 0, stream>>>(
        h, w2_0t, b2_0, feat, feat, BATCH, INDIM, 1024, 1);
    gemm_bf16<<<dim3(1024/128, BATCH/128), 512, 0, stream>>>(
        feat, w1_1t, b1_1, nullptr, h, BATCH, 1024, INDIM, 1);
    gemm_bf16<<<dim3(INDIM/128, BATCH/128), 512, 0, stream>>>(
        h, w2_1t, b2_1, feat, feat, BATCH, INDIM, 1024, 1);
    gemm_bf16<<<dim3(512/128, BATCH/128), 512, 0, stream>>>(
        feat, w1_2t, b1_2, nullptr, h, BATCH, 512, INDIM, 1);
    gemm_bf16<<<dim3(INDIM/128, BATCH/128), 512, 0, stream>>>(
        h, w2_2t, b2_2, feat, feat, BATCH, INDIM, 512, 1);

    // 3) head
    final_head<<<BATCH / 4, 256, 0, stream>>>(feat, linw, linb, out);
}